// Round 5
// baseline (9665.941 us; speedup 1.0000x reference)
//
#include <hip/hip_runtime.h>
#include <hip/hip_bf16.h>

#define BB    128
#define SEQL  336
#define PREDN 24
#define IN    64
#define HH    256
#define GG    1024          // 4*H
#define KTOT  320           // IN + H
#define NBLK  256

// ---- static device scratch (~7 MB .bss; re-initialized by prep every call) ----
__device__ float g_wt_enc[2 * KTOT * GG];    // [dir][k][n][gate] float4-interleaved
__device__ float g_wt_dec[2 * KTOT * GG];
__device__ float g_linwt[2 * HH * IN];       // [k2][o]
__device__ float g_bs_enc[2 * GG];
__device__ float g_bs_dec[2 * GG];
__device__ float g_linb[IN];
__device__ float g_h[2][2 * BB * HH];        // ping-pong [p][dir][b][n]
__device__ float g_c[2 * BB * HH];           // cell state [dir][b][n]
__device__ float g_ys[PREDN * BB * IN];      // fp32 decoder feedback

#define N_WT   (2 * KTOT * GG)               // 655360
#define N_PREP (2 * N_WT + 2 * HH * IN + 4 * GG + IN + 3 * 2 * BB * HH + PREDN * BB * IN)

// Transpose weights into [k][n][gate] (float4 per n), combine biases,
// zero h/c/ys. ALL INPUTS ARE FLOAT32 (per reference dtypes).
__global__ void prep_kernel(const float* __restrict__ eWih,
                            const float* __restrict__ eWhh,
                            const float* __restrict__ ebih,
                            const float* __restrict__ ebhh,
                            const float* __restrict__ dWih,
                            const float* __restrict__ dWhh,
                            const float* __restrict__ dbih,
                            const float* __restrict__ dbhh,
                            const float* __restrict__ linW,
                            const float* __restrict__ linb)
{
    int idx = blockIdx.x * 256 + threadIdx.x;
    if (idx >= N_PREP) return;

    if (idx < N_WT) {                 // enc
        int d  = idx / (KTOT * GG);
        int r2 = idx % (KTOT * GG);
        int k  = r2 / GG;
        int q  = r2 % GG;
        int nn = q >> 2, g = q & 3;
        int j  = g * HH + nn;
        g_wt_enc[idx] = (k < IN) ? eWih[(d * GG + j) * IN + k]
                                 : eWhh[(d * GG + j) * HH + (k - IN)];
        return;
    }
    idx -= N_WT;
    if (idx < N_WT) {                 // dec
        int d  = idx / (KTOT * GG);
        int r2 = idx % (KTOT * GG);
        int k  = r2 / GG;
        int q  = r2 % GG;
        int nn = q >> 2, g = q & 3;
        int j  = g * HH + nn;
        g_wt_dec[idx] = (k < IN) ? dWih[(d * GG + j) * IN + k]
                                 : dWhh[(d * GG + j) * HH + (k - IN)];
        return;
    }
    idx -= N_WT;
    if (idx < 2 * HH * IN) {          // linWT[k2][o]
        int k = idx / IN, o = idx % IN;
        g_linwt[idx] = linW[o * (2 * HH) + k];
        return;
    }
    idx -= 2 * HH * IN;
    if (idx < 2 * GG) { g_bs_enc[idx] = ebih[idx] + ebhh[idx]; return; }
    idx -= 2 * GG;
    if (idx < 2 * GG) { g_bs_dec[idx] = dbih[idx] + dbhh[idx]; return; }
    idx -= 2 * GG;
    if (idx < IN) { g_linb[idx] = linb[idx]; return; }
    idx -= IN;
    if (idx < 2 * 2 * BB * HH) { g_h[0][idx] = 0.0f; return; }   // both ping-pong bufs (contiguous)
    idx -= 2 * 2 * BB * HH;
    if (idx < 2 * BB * HH) { g_c[idx] = 0.0f; return; }
    idx -= 2 * BB * HH;
    if (idx < PREDN * BB * IN) { g_ys[idx] = 0.0f; return; }
}

__device__ __forceinline__ float sigm(float v) { return 1.0f / (1.0f + expf(-v)); }

// One LSTM step for both directions. 256 blocks x 256 threads.
// blk: dir(2) x btile(16, 8 b) x ntile(8, 32 n). Thread: tb=tid>>5 (b), tn=tid&31 (n).
// mode 0: encoder, x timestep tval (dir-reflected). mode 1: decoder t=0, x last step.
// mode 2: decoder, g_ys sub-step tval of length L (dir-reflected).
__global__ __launch_bounds__(256)
void step_kernel(const float* __restrict__ x, int mode, int tval, int L, int p)
{
    __shared__ float acts[8 * KTOT];

    const int tid   = threadIdx.x;
    const int blk   = blockIdx.x;
    const int dir   = blk >> 7;
    const int r     = blk & 127;
    const int ntile = r & 7;
    const int btile = r >> 3;
    const int tn    = tid & 31;
    const int tb    = tid >> 5;
    const int n     = ntile * 32 + tn;
    const int b     = btile * 8 + tb;

    const float* wbase = ((mode == 0) ? g_wt_enc : g_wt_dec) + dir * (KTOT * GG);
    const float* bs    = ((mode == 0) ? g_bs_enc : g_bs_dec) + dir * GG;
    const float* hsrc  = g_h[p];
    float*       hdst  = g_h[p ^ 1];

    // stage activations [8 b][320 k] into LDS
    for (int i = tid; i < 8 * KTOT; i += 256) {
        int bl = i / KTOT;
        int k  = i - bl * KTOT;
        int bg = btile * 8 + bl;
        float v;
        if (k < IN) {
            if (mode == 0)      { int te = dir ? (SEQL - 1 - tval) : tval; v = x[(bg * SEQL + te) * IN + k]; }
            else if (mode == 1) { v = x[(bg * SEQL + (SEQL - 1)) * IN + k]; }
            else                { int e = dir ? (L - 1 - tval) : tval;     v = g_ys[(e * BB + bg) * IN + k]; }
        } else {
            v = hsrc[(dir * BB + bg) * HH + (k - IN)];
        }
        acts[bl * KTOT + k] = v;
    }
    __syncthreads();

    float a0 = bs[n], a1 = bs[256 + n], a2 = bs[512 + n], a3 = bs[768 + n];
    const float4* wp = (const float4*)wbase + n;   // [k][n] float4 (4 gates)
    const float*  ap = acts + tb * KTOT;
    #pragma unroll 8
    for (int k = 0; k < KTOT; ++k) {
        float4 w = wp[k * (GG / 4)];
        float  a = ap[k];
        a0 = fmaf(a, w.x, a0);
        a1 = fmaf(a, w.y, a1);
        a2 = fmaf(a, w.z, a2);
        a3 = fmaf(a, w.w, a3);
    }
    const int hi = (dir * BB + b) * HH + n;
    float c  = g_c[hi];
    float ig = sigm(a0);
    float fg = sigm(a1);
    float gt = tanhf(a2);
    float og = sigm(a3);
    c = fg * c + ig * gt;
    g_c[hi]  = c;
    hdst[hi] = og * tanhf(c);
}

// Linear head for decoder iteration t. 32 blocks x 256 threads. OUTPUT IS FP32.
__global__ __launch_bounds__(256)
void head_kernel(float* __restrict__ out, int t, int p)
{
    const float* hc = g_h[p];
    int flat = blockIdx.x * 256 + threadIdx.x;
    int bb_  = flat >> 6;
    int o    = flat & 63;
    float acc = g_linb[o];
    const float* h0 = hc + bb_ * HH;            // dir 0 final
    const float* h1 = hc + (BB + bb_) * HH;     // dir 1 final
    #pragma unroll 4
    for (int k = 0; k < HH; ++k) acc = fmaf(h0[k], g_linwt[k * IN + o], acc);
    #pragma unroll 4
    for (int k = 0; k < HH; ++k) acc = fmaf(h1[k], g_linwt[(HH + k) * IN + o], acc);
    g_ys[(t * BB + bb_) * IN + o] = acc;                   // fp32 feedback
    out[bb_ * (PREDN * IN) + t * IN + o] = acc;            // fp32 output
}

extern "C" void kernel_launch(void* const* d_in, const int* in_sizes, int n_in,
                              void* d_out, int out_size, void* d_ws, size_t ws_size,
                              hipStream_t stream)
{
    (void)in_sizes; (void)n_in; (void)out_size; (void)d_ws; (void)ws_size;
    const float* x    = (const float*)d_in[0];
    const float* eWih = (const float*)d_in[1];
    const float* eWhh = (const float*)d_in[2];
    const float* ebih = (const float*)d_in[3];
    const float* ebhh = (const float*)d_in[4];
    const float* dWih = (const float*)d_in[5];
    const float* dWhh = (const float*)d_in[6];
    const float* dbih = (const float*)d_in[7];
    const float* dbhh = (const float*)d_in[8];
    const float* linW = (const float*)d_in[9];
    const float* linb = (const float*)d_in[10];
    float* out = (float*)d_out;

    int prep_blocks = (N_PREP + 255) / 256;
    hipLaunchKernelGGL(prep_kernel, dim3(prep_blocks), dim3(256), 0, stream,
                       eWih, eWhh, ebih, ebhh, dWih, dWhh, dbih, dbhh, linW, linb);

    int p = 0;
    // encoder: 336 stream-ordered steps
    for (int t = 0; t < SEQL; ++t) {
        hipLaunchKernelGGL(step_kernel, dim3(NBLK), dim3(256), 0, stream, x, 0, t, 0, p);
        p ^= 1;
    }
    // decoder: 24 iterations
    for (int t = 0; t < PREDN; ++t) {
        int L = t ? t : 1;
        for (int s = 0; s < L; ++s) {
            hipLaunchKernelGGL(step_kernel, dim3(NBLK), dim3(256), 0, stream,
                               x, (t == 0) ? 1 : 2, s, L, p);
            p ^= 1;
        }
        hipLaunchKernelGGL(head_kernel, dim3(32), dim3(256), 0, stream, out, t, p);
    }
}